// Round 8
// baseline (338.512 us; speedup 1.0000x reference)
//
#include <hip/hip_runtime.h>
#include <hip/hip_bf16.h>
#include <cmath>

// Problem constants
#define B_ 2
#define NQ_ 900
#define N_ 4096
#define LOG2E 1.4426950408889634f

typedef __attribute__((ext_vector_type(4))) float f32x4;
typedef __attribute__((ext_vector_type(8))) short s16x8;
typedef __attribute__((ext_vector_type(8))) _Float16 f16x8;

__device__ inline short f2bf(float x) {
    union { __hip_bfloat16 b; short s; } u;
    u.b = __float2bfloat16(x);
    return u.s;
}
__device__ inline short f2h(float x) {
    _Float16 h = (_Float16)x;
    return __builtin_bit_cast(short, h);
}

// DPP rotate within 16-lane row (VALU pipe; replaces ds_bpermute shuffles)
template <int CTRL>
__device__ inline float dppf(float x) {
    int xi = __builtin_bit_cast(int, x);
    int r = __builtin_amdgcn_update_dpp(xi, xi, CTRL, 0xF, 0xF, true);
    return __builtin_bit_cast(float, r);
}
__device__ inline float rowmax16(float v) {
    v = fmaxf(v, dppf<0x121>(v));   // row_ror:1
    v = fmaxf(v, dppf<0x122>(v));   // row_ror:2
    v = fmaxf(v, dppf<0x124>(v));   // row_ror:4
    v = fmaxf(v, dppf<0x128>(v));   // row_ror:8
    return v;
}
__device__ inline float rowsum16(float v) {
    v += dppf<0x121>(v);
    v += dppf<0x122>(v);
    v += dppf<0x124>(v);
    v += dppf<0x128>(v);
    return v;
}

// ---------------------------------------------------------------------------
// Merged Q/K/V projection (blockIdx.z selects matrix). MFMA bf16, 64x64 tile,
// K=256 LDS-resident, quad-interleaved granules (conflict-free LDS).
// B-tile staged directly from fp32 W (column reads, L2-resident; prep kernel
// eliminated). Epilogues: row-major bf16 [b][h][pos][32].
// ---------------------------------------------------------------------------
__global__ __launch_bounds__(256) void proj_kernel(
    const float* __restrict__ query, const float* __restrict__ kin,
    const float* __restrict__ vin,
    const float* __restrict__ Wq, const float* __restrict__ Wk,
    const float* __restrict__ Wv,
    const float* __restrict__ bqv, const float* __restrict__ bkv,
    const float* __restrict__ bvv,
    unsigned short* __restrict__ qbf, unsigned short* __restrict__ kbf,
    unsigned short* __restrict__ vbf, float qscale)
{
    const int mtx = blockIdx.z;
    const float* X = mtx == 0 ? query : mtx == 1 ? kin : vin;
    const float* W = mtx == 0 ? Wq : mtx == 1 ? Wk : Wv;
    const float* bias = mtx == 0 ? bqv : mtx == 1 ? bkv : bvv;
    unsigned short* Y = mtx == 0 ? qbf : mtx == 1 ? kbf : vbf;
    const int M = mtx == 0 ? 1800 : 8192;
    const int m0 = blockIdx.x * 64;
    if (m0 >= M) return;
    const int n0 = blockIdx.y * 64;
    const float alpha = mtx == 0 ? qscale : 1.0f;
    const int rows_per_b = mtx == 0 ? 900 : 4096;
    const int ROWS = mtx == 0 ? 960 : 4096;

    __shared__ short Ab[16384];    // 32 KB, granule (kc*256 + m*4 + quad)
    __shared__ short Bb[16384];
    const int tid = threadIdx.x;
    const int w = tid >> 6, l = tid & 63, quad = l >> 4, l15 = l & 15;

    {
        const int wq = tid & 3, mm = tid >> 2;
        const bool valid = (m0 + mm) < M;
        const float* xr = X + (size_t)(m0 + mm) * 256;
        const float* wcol = W + n0 + mm;          // column n0+mm of W[k][n]
        #pragma unroll
        for (int it = 0; it < 8; ++it) {
            int g2 = it * 4 + wq;
            float4 a0 = make_float4(0.f, 0.f, 0.f, 0.f), a1 = a0;
            if (valid) {
                a0 = *(const float4*)(xr + g2 * 8);
                a1 = *(const float4*)(xr + g2 * 8 + 4);
            }
            uint4 pk;
            pk.x = (unsigned)(unsigned short)f2bf(a0.x) | ((unsigned)(unsigned short)f2bf(a0.y) << 16);
            pk.y = (unsigned)(unsigned short)f2bf(a0.z) | ((unsigned)(unsigned short)f2bf(a0.w) << 16);
            pk.z = (unsigned)(unsigned short)f2bf(a1.x) | ((unsigned)(unsigned short)f2bf(a1.y) << 16);
            pk.w = (unsigned)(unsigned short)f2bf(a1.z) | ((unsigned)(unsigned short)f2bf(a1.w) << 16);
            *(uint4*)(Ab + (it * 256 + mm * 4 + wq) * 8) = pk;
            // B granule: k = it*32 + wq*8 + j, n = n0+mm  (reads W[k][n] column)
            uint4 wk4;
            wk4.x = (unsigned)(unsigned short)f2bf(wcol[(g2 * 8 + 0) * 256])
                  | ((unsigned)(unsigned short)f2bf(wcol[(g2 * 8 + 1) * 256]) << 16);
            wk4.y = (unsigned)(unsigned short)f2bf(wcol[(g2 * 8 + 2) * 256])
                  | ((unsigned)(unsigned short)f2bf(wcol[(g2 * 8 + 3) * 256]) << 16);
            wk4.z = (unsigned)(unsigned short)f2bf(wcol[(g2 * 8 + 4) * 256])
                  | ((unsigned)(unsigned short)f2bf(wcol[(g2 * 8 + 5) * 256]) << 16);
            wk4.w = (unsigned)(unsigned short)f2bf(wcol[(g2 * 8 + 6) * 256])
                  | ((unsigned)(unsigned short)f2bf(wcol[(g2 * 8 + 7) * 256]) << 16);
            *(uint4*)(Bb + (it * 256 + mm * 4 + wq) * 8) = wk4;
        }
    }
    __syncthreads();

    f32x4 acc[4] = {{0.f,0.f,0.f,0.f},{0.f,0.f,0.f,0.f},{0.f,0.f,0.f,0.f},{0.f,0.f,0.f,0.f}};
    #pragma unroll
    for (int kc = 0; kc < 8; ++kc) {
        s16x8 a = *(const s16x8*)(Ab + (kc * 256 + (w * 16 + l15) * 4 + quad) * 8);
        #pragma unroll
        for (int nt = 0; nt < 4; ++nt) {
            s16x8 bf = *(const s16x8*)(Bb + (kc * 256 + (nt * 16 + l15) * 4 + quad) * 8);
            acc[nt] = __builtin_amdgcn_mfma_f32_16x16x32_bf16(a, bf, acc[nt], 0, 0, 0);
        }
    }

    #pragma unroll
    for (int nt = 0; nt < 4; ++nt) {
        int n = n0 + nt * 16 + l15;
        float bs = bias[n];
        int h = n >> 5, d = n & 31;
        #pragma unroll
        for (int r = 0; r < 4; ++r) {
            int row = m0 + w * 16 + quad * 4 + r;
            if (row < M) {
                int b = row / rows_per_b;
                int pos = row - b * rows_per_b;
                Y[((size_t)(b * 8 + h) * ROWS + pos) * 32 + d] =
                    (unsigned short)f2bf((acc[nt][r] + bs) * alpha);
            }
        }
    }
}

// ---------------------------------------------------------------------------
// fp32 GEMM for the output projection (precision-critical; stays fp32).
// ---------------------------------------------------------------------------
__global__ __launch_bounds__(256) void gemm_bias_kernel(
    const float* __restrict__ X, const float* __restrict__ W,
    const float* __restrict__ bias, float* __restrict__ Y,
    int M, float alpha)
{
    __shared__ float As[16][65];
    __shared__ float Bs[16][64];
    const int tid = threadIdx.x;
    const int tx = tid & 15, ty = tid >> 4;
    const int m0 = blockIdx.x * 64;
    const int n0 = blockIdx.y * 64;
    const int arow = tid >> 2, acol4 = tid & 3;
    const int brow = tid >> 4, bcol4 = tid & 15;

    float acc[4][4] = {};
    for (int k0 = 0; k0 < 256; k0 += 16) {
        float4 av = make_float4(0.f, 0.f, 0.f, 0.f);
        if (m0 + arow < M)
            av = *(const float4*)(X + (size_t)(m0 + arow) * 256 + k0 + acol4 * 4);
        As[acol4 * 4 + 0][arow] = av.x;
        As[acol4 * 4 + 1][arow] = av.y;
        As[acol4 * 4 + 2][arow] = av.z;
        As[acol4 * 4 + 3][arow] = av.w;
        float4 bv = *(const float4*)(W + (size_t)(k0 + brow) * 256 + n0 + bcol4 * 4);
        *(float4*)(&Bs[brow][bcol4 * 4]) = bv;
        __syncthreads();
        #pragma unroll
        for (int k = 0; k < 16; ++k) {
            float4 b4 = *(const float4*)(&Bs[k][tx * 4]);
            #pragma unroll
            for (int i = 0; i < 4; ++i) {
                float a = As[k][ty * 4 + i];
                acc[i][0] = fmaf(a, b4.x, acc[i][0]);
                acc[i][1] = fmaf(a, b4.y, acc[i][1]);
                acc[i][2] = fmaf(a, b4.z, acc[i][2]);
                acc[i][3] = fmaf(a, b4.w, acc[i][3]);
            }
        }
        __syncthreads();
    }
    #pragma unroll
    for (int i = 0; i < 4; ++i) {
        int mrow = m0 + ty * 4 + i;
        if (mrow < M) {
            int n = n0 + tx * 4;
            float4 o;
            o.x = (acc[i][0] + bias[n + 0]) * alpha;
            o.y = (acc[i][1] + bias[n + 1]) * alpha;
            o.z = (acc[i][2] + bias[n + 2]) * alpha;
            o.w = (acc[i][3] + bias[n + 3]) * alpha;
            *(float4*)(Y + (size_t)mrow * 256 + n) = o;
        }
    }
}

// ---------------------------------------------------------------------------
// RPE via fp16-split MFMA. W2 hi/lo split (×LOG2E) done in-block (prep kernel
// eliminated; W2 is 16 KB/axis, L2-resident).
// ---------------------------------------------------------------------------
__global__ __launch_bounds__(256) void rpe2_kernel(
    const float* __restrict__ ref2d,
    const float* __restrict__ W1x, const float* __restrict__ b1x,
    const float* __restrict__ W1y, const float* __restrict__ b1y,
    const float* __restrict__ W2x, const float* __restrict__ W2y,
    float* __restrict__ rpe_x, float* __restrict__ rpe_y)
{
    __shared__ short sw2h[8192], sw2l[8192];
    __shared__ float4 sW1i[512];
    __shared__ float2 sB1i[512];
    __shared__ short hxh[64 * 40], hxl[64 * 40], hyh[64 * 40], hyl[64 * 40];

    const int tid = threadIdx.x;
    const int bq = blockIdx.x;
    for (int i = tid; i < 512; i += 256) {
        sW1i[i] = make_float4(W1x[i], W1x[512 + i], W1y[i], W1y[512 + i]);
        sB1i[i] = make_float2(b1x[i], b1y[i]);
    }
    for (int i = tid; i < 8192; i += 256) {
        int g = i >> 3, j = i & 7;
        int kcg = g >> 6, rr = g & 63, n = rr >> 2, q4 = rr & 3;
        int k = kcg * 32 + q4 * 8 + j;
        float val = ((n < 8) ? W2x[k * 8 + n] : W2y[k * 8 + (n - 8)]) * LOG2E;
        _Float16 hi = (_Float16)val;
        sw2h[i] = __builtin_bit_cast(short, hi);
        sw2l[i] = f2h(val - (float)hi);
    }
    const float4 box = *(const float4*)(ref2d + (size_t)bq * 4);

    const int w = tid >> 6, l = tid & 63, quad = l >> 4, l15 = l & 15;
    const int r = l;
    const float pc = (r + 0.5f) * 16.0f;
    const float dx0 = (box.x - box.z * 0.5f) - pc;
    const float dx1 = (box.x + box.z * 0.5f) - pc;
    const float dy0 = (box.y - box.w * 0.5f) - pc;
    const float dy1 = (box.y + box.w * 0.5f) - pc;

    f32x4 accx = {0.f, 0.f, 0.f, 0.f}, accy = {0.f, 0.f, 0.f, 0.f};
    __syncthreads();

    for (int kc = 0; kc < 16; ++kc) {
        unsigned short vxh[8], vxl[8], vyh[8], vyl[8];
        #pragma unroll
        for (int i = 0; i < 8; ++i) {
            int j = kc * 32 + w * 8 + i;
            float4 w1 = sW1i[j];
            float2 bb = sB1i[j];
            float hx = fmaxf(fmaf(dx0, w1.x, fmaf(dx1, w1.y, bb.x)), 0.f);
            float hy = fmaxf(fmaf(dy0, w1.z, fmaf(dy1, w1.w, bb.y)), 0.f);
            _Float16 xh = (_Float16)hx;
            _Float16 yh = (_Float16)hy;
            vxh[i] = (unsigned short)__builtin_bit_cast(short, xh);
            vyh[i] = (unsigned short)__builtin_bit_cast(short, yh);
            vxl[i] = (unsigned short)f2h(hx - (float)xh);
            vyl[i] = (unsigned short)f2h(hy - (float)yh);
        }
        __syncthreads();
        uint4 p;
        p.x = vxh[0] | ((unsigned)vxh[1] << 16); p.y = vxh[2] | ((unsigned)vxh[3] << 16);
        p.z = vxh[4] | ((unsigned)vxh[5] << 16); p.w = vxh[6] | ((unsigned)vxh[7] << 16);
        *(uint4*)(hxh + r * 40 + w * 8) = p;
        p.x = vxl[0] | ((unsigned)vxl[1] << 16); p.y = vxl[2] | ((unsigned)vxl[3] << 16);
        p.z = vxl[4] | ((unsigned)vxl[5] << 16); p.w = vxl[6] | ((unsigned)vxl[7] << 16);
        *(uint4*)(hxl + r * 40 + w * 8) = p;
        p.x = vyh[0] | ((unsigned)vyh[1] << 16); p.y = vyh[2] | ((unsigned)vyh[3] << 16);
        p.z = vyh[4] | ((unsigned)vyh[5] << 16); p.w = vyh[6] | ((unsigned)vyh[7] << 16);
        *(uint4*)(hyh + r * 40 + w * 8) = p;
        p.x = vyl[0] | ((unsigned)vyl[1] << 16); p.y = vyl[2] | ((unsigned)vyl[3] << 16);
        p.z = vyl[4] | ((unsigned)vyl[5] << 16); p.w = vyl[6] | ((unsigned)vyl[7] << 16);
        *(uint4*)(hyl + r * 40 + w * 8) = p;
        __syncthreads();

        f16x8 axh = *(const f16x8*)(hxh + (w * 16 + l15) * 40 + quad * 8);
        f16x8 axl = *(const f16x8*)(hxl + (w * 16 + l15) * 40 + quad * 8);
        f16x8 ayh = *(const f16x8*)(hyh + (w * 16 + l15) * 40 + quad * 8);
        f16x8 ayl = *(const f16x8*)(hyl + (w * 16 + l15) * 40 + quad * 8);
        f16x8 bh = *(const f16x8*)(sw2h + (kc * 64 + l15 * 4 + quad) * 8);
        f16x8 bl = *(const f16x8*)(sw2l + (kc * 64 + l15 * 4 + quad) * 8);
        accx = __builtin_amdgcn_mfma_f32_16x16x32_f16(axh, bh, accx, 0, 0, 0);
        accx = __builtin_amdgcn_mfma_f32_16x16x32_f16(axh, bl, accx, 0, 0, 0);
        accx = __builtin_amdgcn_mfma_f32_16x16x32_f16(axl, bh, accx, 0, 0, 0);
        accy = __builtin_amdgcn_mfma_f32_16x16x32_f16(ayh, bh, accy, 0, 0, 0);
        accy = __builtin_amdgcn_mfma_f32_16x16x32_f16(ayh, bl, accy, 0, 0, 0);
        accy = __builtin_amdgcn_mfma_f32_16x16x32_f16(ayl, bh, accy, 0, 0, 0);
    }

    #pragma unroll
    for (int rr = 0; rr < 4; ++rr) {
        int row = w * 16 + quad * 4 + rr;
        size_t base = ((size_t)bq * 64 + row) * 8;
        if (l15 < 8) rpe_x[base + l15] = accx[rr];
        else         rpe_y[base + (l15 - 8)] = accy[rr];
    }
}

// ---------------------------------------------------------------------------
// MFMA flash attention. LDS diet for 3 blocks/CU: no rx tile (rx4 loaded
// straight from global into the MFMA C-operand), mask as 64xu64 ballot
// bitmask (wave-uniform skip when zero), obuf reuses skf. 8 waves = 2 qsub
// x 4 ksplits; DPP softmax; exp2-domain scores.
// ---------------------------------------------------------------------------
__global__ __launch_bounds__(512, 6) void attn_mfma_kernel(
    const unsigned short* __restrict__ qb16, const unsigned short* __restrict__ kb16,
    const unsigned short* __restrict__ vb16,
    const float* __restrict__ rpe_x, const float* __restrict__ rpe_y,
    const unsigned char* __restrict__ mask, float* __restrict__ xout)
{
    __shared__ short skf[4 * 2048];      // 16 KB K frags; reused as obuf
    __shared__ short svt[4 * 2048];      // 16 KB V^T (XOR-swizzled granules)
    __shared__ short spb[8 * 544];       // 8.7 KB P buf per wave
    __shared__ float ry[32 * 65];        // 8.3 KB
    __shared__ unsigned long long smaskb[64];   // 512 B mask bitmasks
    __shared__ float sm[8][16], sl[8][16], sLf[32];

    const int tid = threadIdx.x;
    const int qb = blockIdx.x, h = blockIdx.y, b = blockIdx.z;
    const int q0 = qb * 32;
    const int w = tid >> 6, l = tid & 63;
    const int qsub = w >> 2, g = w & 3;
    const int quad = l >> 4, l15 = l & 15;

    const unsigned short* qg = qb16 + (size_t)(b * 8 + h) * 960 * 32;
    const unsigned short* kg = kb16 + (size_t)(b * 8 + h) * 4096 * 32;
    const unsigned short* vg = vb16 + (size_t)(b * 8 + h) * 4096 * 32;

    for (int i = tid; i < 2048; i += 512) {
        int qq = q0 + (i >> 6), pos = i & 63;
        float vy = 0.f;
        if (qq < NQ_)
            vy = rpe_y[((size_t)(b * NQ_ + qq) * 64 + pos) * 8 + h];
        ry[(i >> 6) * 65 + pos] = vy;
    }
    #pragma unroll
    for (int j = 0; j < 8; ++j) {        // wave w builds bitmasks for chunks w*8..w*8+7
        int c = w * 8 + j;
        unsigned long long bits = __ballot(mask[(size_t)b * N_ + c * 64 + l] != 0);
        if (l == 0) smaskb[c] = bits;
    }

    s16x8 qa = *(const s16x8*)(qg + (size_t)(q0 + qsub * 16 + l15) * 32 + quad * 8);

    // rpe_x fragment straight from global (L2-resident), as MFMA C-operand
    f32x4 rx4[4];
    #pragma unroll
    for (int t = 0; t < 4; ++t)
        #pragma unroll
        for (int r = 0; r < 4; ++r) {
            int qq = q0 + qsub * 16 + quad * 4 + r;
            rx4[t][r] = (qq < NQ_)
                ? rpe_x[((size_t)(b * NQ_ + qq) * 64 + t * 16 + l15) * 8 + h] : 0.f;
        }

    // staging roles: sg = ksplit (tid>>7), role 0 = K frags, role 1 = V rows
    const int sg = tid >> 7, role = (tid >> 6) & 1, stl = tid & 63;
    int eoff[4];
    if (role == 0) {
        #pragma unroll
        for (int t = 0; t < 4; ++t)
            eoff[t] = (t * 16 + (stl & 15)) * 32 + (stl >> 4) * 8;
    } else {
        #pragma unroll
        for (int t = 0; t < 4; ++t)
            eoff[t] = stl * 32 + t * 8;          // key stl, d = t*8..t*8+7
    }
    const unsigned short* src = role ? vg : kg;

    uint4 pf[4];
    {
        size_t cb = (size_t)(sg * 16) * 2048;
        #pragma unroll
        for (int t = 0; t < 4; ++t) pf[t] = *(const uint4*)(src + cb + eoff[t]);
    }

    float mrow[4] = {-INFINITY, -INFINITY, -INFINITY, -INFINITY};
    float lrow[4] = {0.f, 0.f, 0.f, 0.f};
    f32x4 acc0 = {0.f, 0.f, 0.f, 0.f}, acc1 = {0.f, 0.f, 0.f, 0.f};
    short* pw = spb + w * 544;

    for (int i = 0; i < 16; ++i) {
        __syncthreads();                 // also covers ry/smaskb on i=0
        if (role == 0) {
            #pragma unroll
            for (int t = 0; t < 4; ++t)
                *(uint4*)(skf + sg * 2048 + (t * 64 + stl) * 8) = pf[t];
        } else {
            short* vtw = svt + sg * 2048;
            #pragma unroll
            for (int t = 0; t < 4; ++t) {
                const unsigned short* pv = (const unsigned short*)&pf[t];
                #pragma unroll
                for (int j = 0; j < 8; ++j) {
                    int d = t * 8 + j;
                    vtw[d * 64 + (((stl >> 3) ^ (d & 7)) << 3) + (stl & 7)] = (short)pv[j];
                }
            }
        }
        __syncthreads();

        {
            int inext = (i + 1 < 16) ? i + 1 : 15;
            size_t cb = (size_t)(sg * 16 + inext) * 2048;
            #pragma unroll
            for (int t = 0; t < 4; ++t) pf[t] = *(const uint4*)(src + cb + eoff[t]);
        }

        const int cgc = g * 16 + i;
        const short* kf = skf + g * 2048;

        // QK^T with rpe_x pre-loaded in the accumulator
        f32x4 sc[4];
        #pragma unroll
        for (int t = 0; t < 4; ++t) {
            s16x8 kb = *(const s16x8*)(kf + (t * 64 + l) * 8);
            sc[t] = __builtin_amdgcn_mfma_f32_16x16x32_bf16(qa, kb, rx4[t], 0, 0, 0);
        }
        float ryv[4];
        #pragma unroll
        for (int r = 0; r < 4; ++r)
            ryv[r] = ry[(qsub * 16 + quad * 4 + r) * 65 + cgc];
        unsigned long long mb = smaskb[cgc];
        if (mb) {                        // wave-uniform skip (masks usually 0)
            #pragma unroll
            for (int t = 0; t < 4; ++t) {
                float mk = ((mb >> (t * 16 + l15)) & 1ULL) ? -144.2695f : 0.f;
                #pragma unroll
                for (int r = 0; r < 4; ++r) sc[t][r] += mk;
            }
        }
        #pragma unroll
        for (int t = 0; t < 4; ++t)
            #pragma unroll
            for (int r = 0; r < 4; ++r)
                sc[t][r] += ryv[r];

        float cm[4];
        #pragma unroll
        for (int r = 0; r < 4; ++r) {
            cm[r] = fmaxf(fmaxf(sc[0][r], sc[1][r]), fmaxf(sc[2][r], sc[3][r]));
            cm[r] = rowmax16(cm[r]);
        }
        float al[4];
        #pragma unroll
        for (int r = 0; r < 4; ++r) {
            float mnew = fmaxf(mrow[r], cm[r]);
            al[r] = exp2f(mrow[r] - mnew);
            mrow[r] = mnew;
            lrow[r] *= al[r];
            acc0[r] *= al[r];
            acc1[r] *= al[r];
        }
        #pragma unroll
        for (int t = 0; t < 4; ++t)
            #pragma unroll
            for (int r = 0; r < 4; ++r)
                sc[t][r] = exp2f(sc[t][r] - mrow[r]);
        #pragma unroll
        for (int r = 0; r < 4; ++r) {
            float rs = (sc[0][r] + sc[1][r]) + (sc[2][r] + sc[3][r]);
            lrow[r] += rowsum16(rs);
        }

        const short* vt = svt + g * 2048;
        #pragma unroll
        for (int hh = 0; hh < 2; ++hh) {
            #pragma unroll
            for (int tt = 0; tt < 2; ++tt) {
                int t = hh * 2 + tt;
                int gphys = (tt * 2 + (l15 >> 3)) ^ quad;
                #pragma unroll
                for (int r = 0; r < 4; ++r)
                    pw[(gphys * 17 + quad * 4 + r) * 8 + (l15 & 7)] = f2bf(sc[t][r]);
            }
            int gph_r = quad ^ (l15 >> 2);
            s16x8 pa  = *(const s16x8*)(pw + (gph_r * 17 + l15) * 8);
            int ksw = ((hh * 4 + quad) ^ (l15 & 7)) * 8;
            s16x8 vb0 = *(const s16x8*)(vt + l15 * 64 + ksw);
            s16x8 vb1 = *(const s16x8*)(vt + (16 + l15) * 64 + ksw);
            acc0 = __builtin_amdgcn_mfma_f32_16x16x32_bf16(pa, vb0, acc0, 0, 0, 0);
            acc1 = __builtin_amdgcn_mfma_f32_16x16x32_bf16(pa, vb1, acc1, 0, 0, 0);
        }
    }

    __syncthreads();
    if (l15 == 0) {
        #pragma unroll
        for (int r = 0; r < 4; ++r) {
            sm[w][quad * 4 + r] = mrow[r];
            sl[w][quad * 4 + r] = lrow[r];
        }
    }
    __syncthreads();
    float wgt[4], L4[4];
    #pragma unroll
    for (int r = 0; r < 4; ++r) {
        int qrow = quad * 4 + r;
        float mm = -INFINITY;
        #pragma unroll
        for (int gg = 0; gg < 4; ++gg) mm = fmaxf(mm, sm[qsub * 4 + gg][qrow]);
        float LL = 0.f;
        #pragma unroll
        for (int gg = 0; gg < 4; ++gg)
            LL += exp2f(sm[qsub * 4 + gg][qrow] - mm) * sl[qsub * 4 + gg][qrow];
        wgt[r] = exp2f(mrow[r] - mm);
        L4[r] = LL;
    }
    if (g == 0 && l15 == 0) {
        #pragma unroll
        for (int r = 0; r < 4; ++r) sLf[qsub * 16 + quad * 4 + r] = L4[r];
    }

    float* obuf = (float*)skf;           // 32x33 fp32 = 4.2 KB (skf is done)
    for (int gg = 0; gg < 4; ++gg) {
        if (g == gg) {
            #pragma unroll
            for (int r = 0; r < 4; ++r) {
                int idx = (qsub * 16 + quad * 4 + r) * 33 + l15;
                float v0 = wgt[r] * acc0[r];
                float v1 = wgt[r] * acc1[r];
                if (gg == 0) { obuf[idx] = v0; obuf[idx + 16] = v1; }
                else         { obuf[idx] += v0; obuf[idx + 16] += v1; }
            }
        }
        __syncthreads();
    }

    for (int i = tid; i < 1024; i += 512) {
        int ql = i >> 5, d = i & 31;
        int qq = q0 + ql;
        if (qq < NQ_)
            xout[(size_t)(b * NQ_ + qq) * 256 + h * 32 + d] = obuf[ql * 33 + d] / sLf[ql];
    }
}

// ---------------------------------------------------------------------------
extern "C" void kernel_launch(void* const* d_in, const int* in_sizes, int n_in,
                              void* d_out, int out_size, void* d_ws, size_t ws_size,
                              hipStream_t stream)
{
    const float* query = (const float*)d_in[1];
    const float* ref2d = (const float*)d_in[2];
    const float* kin   = (const float*)d_in[3];
    const float* vin   = (const float*)d_in[4];
    const unsigned char* mask = (const unsigned char*)d_in[6];
    const float* W1x = (const float*)d_in[7];
    const float* b1x = (const float*)d_in[8];
    const float* W2x = (const float*)d_in[9];
    const float* W1y = (const float*)d_in[10];
    const float* b1y = (const float*)d_in[11];
    const float* W2y = (const float*)d_in[12];
    const float* Wq  = (const float*)d_in[13];
    const float* bq  = (const float*)d_in[14];
    const float* Wk  = (const float*)d_in[15];
    const float* bk  = (const float*)d_in[16];
    const float* Wv  = (const float*)d_in[17];
    const float* bv  = (const float*)d_in[18];
    const float* Wp  = (const float*)d_in[19];
    const float* bp  = (const float*)d_in[20];

    // Workspace ~18.6 MB (proven-safe footprint 27.8 MB)
    char* wsb = (char*)d_ws;
    unsigned short* qbf = (unsigned short*)(wsb);               //   983040 B
    unsigned short* kbf = (unsigned short*)(wsb +   983040);    //  4194304 B
    unsigned short* vbf = (unsigned short*)(wsb +  5177344);    //  4194304 B
    float* rxws = (float*)(wsb +  9371648);                     //  3686400 B
    float* ryws = (float*)(wsb + 13058048);                     //  3686400 B
    float* xws  = (float*)(wsb + 16744448);                     //  1843200 B
    float* out  = (float*)d_out;

    const float qscale = LOG2E / sqrtf(32.0f);   // exp2-domain softmax

    proj_kernel<<<dim3(128, 4, 3), 256, 0, stream>>>(
        query, kin, vin, Wq, Wk, Wv, bq, bk, bv, qbf, kbf, vbf, qscale);
    rpe2_kernel<<<1800, 256, 0, stream>>>(
        ref2d, W1x, b1x, W1y, b1y, W2x, W2y, rxws, ryws);
    attn_mfma_kernel<<<dim3(29, 8, B_), 512, 0, stream>>>(
        qbf, kbf, vbf, rxws, ryws, mask, xws);
    gemm_bias_kernel<<<dim3(29, 4), 256, 0, stream>>>(xws, Wp, bp, out, 1800, 1.0f);
}

// Round 9
// 276.525 us; speedup vs baseline: 1.2242x; 1.2242x over previous
//
#include <hip/hip_runtime.h>
#include <hip/hip_bf16.h>
#include <cmath>

// Problem constants
#define B_ 2
#define NQ_ 900
#define N_ 4096
#define LOG2E 1.4426950408889634f

typedef __attribute__((ext_vector_type(4))) float f32x4;
typedef __attribute__((ext_vector_type(8))) short s16x8;
typedef __attribute__((ext_vector_type(8))) _Float16 f16x8;

__device__ inline short f2bf(float x) {
    union { __hip_bfloat16 b; short s; } u;
    u.b = __float2bfloat16(x);
    return u.s;
}
__device__ inline short f2h(float x) {
    _Float16 h = (_Float16)x;
    return __builtin_bit_cast(short, h);
}

// DPP rotate within 16-lane row (VALU pipe; replaces ds_bpermute shuffles)
template <int CTRL>
__device__ inline float dppf(float x) {
    int xi = __builtin_bit_cast(int, x);
    int r = __builtin_amdgcn_update_dpp(xi, xi, CTRL, 0xF, 0xF, true);
    return __builtin_bit_cast(float, r);
}
__device__ inline float rowmax16(float v) {
    v = fmaxf(v, dppf<0x121>(v));
    v = fmaxf(v, dppf<0x122>(v));
    v = fmaxf(v, dppf<0x124>(v));
    v = fmaxf(v, dppf<0x128>(v));
    return v;
}
__device__ inline float rowsum16(float v) {
    v += dppf<0x121>(v);
    v += dppf<0x122>(v);
    v += dppf<0x124>(v);
    v += dppf<0x128>(v);
    return v;
}

// ---------------------------------------------------------------------------
// Merged Q/K/V projection. MFMA bf16, 64-row tile, K=256 LDS-resident A
// staged ONCE, then the four 64-col n-tiles looped in-block (X HBM reads
// down ~4x vs one-block-per-(m,n)). Epilogue: row-major bf16 [b][h][pos][32].
// ---------------------------------------------------------------------------
__global__ __launch_bounds__(256) void proj_kernel(
    const float* __restrict__ query, const float* __restrict__ kin,
    const float* __restrict__ vin,
    const float* __restrict__ Wq, const float* __restrict__ Wk,
    const float* __restrict__ Wv,
    const float* __restrict__ bqv, const float* __restrict__ bkv,
    const float* __restrict__ bvv,
    unsigned short* __restrict__ qbf, unsigned short* __restrict__ kbf,
    unsigned short* __restrict__ vbf, float qscale)
{
    const int mtx = blockIdx.z;
    const float* X = mtx == 0 ? query : mtx == 1 ? kin : vin;
    const float* W = mtx == 0 ? Wq : mtx == 1 ? Wk : Wv;
    const float* bias = mtx == 0 ? bqv : mtx == 1 ? bkv : bvv;
    unsigned short* Y = mtx == 0 ? qbf : mtx == 1 ? kbf : vbf;
    const int M = mtx == 0 ? 1800 : 8192;
    const int m0 = blockIdx.x * 64;
    if (m0 >= M) return;
    const float alpha = mtx == 0 ? qscale : 1.0f;
    const int rows_per_b = mtx == 0 ? 900 : 4096;
    const int ROWS = mtx == 0 ? 960 : 4096;

    __shared__ short Ab[16384];    // 32 KB, granule (kc*256 + m*4 + quad)
    __shared__ short Bb[16384];
    const int tid = threadIdx.x;
    const int w = tid >> 6, l = tid & 63, quad = l >> 4, l15 = l & 15;
    const int wq = tid & 3, mm = tid >> 2;

    // A tile staged once (fp32 -> bf16 convert in staging)
    {
        const bool valid = (m0 + mm) < M;
        const float* xr = X + (size_t)(m0 + mm) * 256;
        #pragma unroll
        for (int it = 0; it < 8; ++it) {
            int g2 = it * 4 + wq;
            float4 a0 = make_float4(0.f, 0.f, 0.f, 0.f), a1 = a0;
            if (valid) {
                a0 = *(const float4*)(xr + g2 * 8);
                a1 = *(const float4*)(xr + g2 * 8 + 4);
            }
            uint4 pk;
            pk.x = (unsigned)(unsigned short)f2bf(a0.x) | ((unsigned)(unsigned short)f2bf(a0.y) << 16);
            pk.y = (unsigned)(unsigned short)f2bf(a0.z) | ((unsigned)(unsigned short)f2bf(a0.w) << 16);
            pk.z = (unsigned)(unsigned short)f2bf(a1.x) | ((unsigned)(unsigned short)f2bf(a1.y) << 16);
            pk.w = (unsigned)(unsigned short)f2bf(a1.z) | ((unsigned)(unsigned short)f2bf(a1.w) << 16);
            *(uint4*)(Ab + (it * 256 + mm * 4 + wq) * 8) = pk;
        }
    }

    for (int nt0 = 0; nt0 < 4; ++nt0) {
        const int n0 = nt0 * 64;
        // B tile: columns n0+mm of fp32 W[k][n]
        {
            const float* wcol = W + n0 + mm;
            #pragma unroll
            for (int it = 0; it < 8; ++it) {
                int g2 = it * 4 + wq;
                uint4 wk4;
                wk4.x = (unsigned)(unsigned short)f2bf(wcol[(g2 * 8 + 0) * 256])
                      | ((unsigned)(unsigned short)f2bf(wcol[(g2 * 8 + 1) * 256]) << 16);
                wk4.y = (unsigned)(unsigned short)f2bf(wcol[(g2 * 8 + 2) * 256])
                      | ((unsigned)(unsigned short)f2bf(wcol[(g2 * 8 + 3) * 256]) << 16);
                wk4.z = (unsigned)(unsigned short)f2bf(wcol[(g2 * 8 + 4) * 256])
                      | ((unsigned)(unsigned short)f2bf(wcol[(g2 * 8 + 5) * 256]) << 16);
                wk4.w = (unsigned)(unsigned short)f2bf(wcol[(g2 * 8 + 6) * 256])
                      | ((unsigned)(unsigned short)f2bf(wcol[(g2 * 8 + 7) * 256]) << 16);
                *(uint4*)(Bb + (it * 256 + mm * 4 + wq) * 8) = wk4;
            }
        }
        __syncthreads();   // A (on nt0=0) + B visible

        f32x4 acc[4] = {{0.f,0.f,0.f,0.f},{0.f,0.f,0.f,0.f},{0.f,0.f,0.f,0.f},{0.f,0.f,0.f,0.f}};
        #pragma unroll
        for (int kc = 0; kc < 8; ++kc) {
            s16x8 a = *(const s16x8*)(Ab + (kc * 256 + (w * 16 + l15) * 4 + quad) * 8);
            #pragma unroll
            for (int nt = 0; nt < 4; ++nt) {
                s16x8 bf = *(const s16x8*)(Bb + (kc * 256 + (nt * 16 + l15) * 4 + quad) * 8);
                acc[nt] = __builtin_amdgcn_mfma_f32_16x16x32_bf16(a, bf, acc[nt], 0, 0, 0);
            }
        }
        __syncthreads();   // MFMA reads done before next B restage

        #pragma unroll
        for (int nt = 0; nt < 4; ++nt) {
            int n = n0 + nt * 16 + l15;
            float bs = bias[n];
            int h = n >> 5, d = n & 31;
            #pragma unroll
            for (int r = 0; r < 4; ++r) {
                int row = m0 + w * 16 + quad * 4 + r;
                if (row < M) {
                    int b = row / rows_per_b;
                    int pos = row - b * rows_per_b;
                    Y[((size_t)(b * 8 + h) * ROWS + pos) * 32 + d] =
                        (unsigned short)f2bf((acc[nt][r] + bs) * alpha);
                }
            }
        }
    }
}

// ---------------------------------------------------------------------------
// Output projection via fp16 hi/lo split MFMA (3-chain: ~2^-22 precision).
// K staged in 4 quarters of 64 (Ah/Al/Bh/Bl = 32 KB LDS). Output fp32.
// ---------------------------------------------------------------------------
__global__ __launch_bounds__(256) void outproj_kernel(
    const float* __restrict__ X, const float* __restrict__ W,
    const float* __restrict__ bias, float* __restrict__ Y, int M)
{
    __shared__ short Abh[4096], Abl[4096], Bbh[4096], Bbl[4096];
    const int tid = threadIdx.x;
    const int m0 = blockIdx.x * 64, n0 = blockIdx.y * 64;
    const int w = tid >> 6, l = tid & 63, quad = l >> 4, l15 = l & 15;
    const int wq = tid & 3, mm = tid >> 2;
    const bool valid = (m0 + mm) < M;
    const float* xr = X + (size_t)(m0 + mm) * 256;
    const float* wcol = W + n0 + mm;

    f32x4 acc[4] = {{0.f,0.f,0.f,0.f},{0.f,0.f,0.f,0.f},{0.f,0.f,0.f,0.f},{0.f,0.f,0.f,0.f}};

    for (int kq = 0; kq < 4; ++kq) {
        #pragma unroll
        for (int it = 0; it < 2; ++it) {
            int g2 = it * 4 + wq;                 // 0..7 within quarter
            int kbase = kq * 64 + g2 * 8;
            float av[8], bv[8];
            #pragma unroll
            for (int j = 0; j < 8; ++j) {
                av[j] = valid ? xr[kbase + j] : 0.f;
                bv[j] = wcol[(kbase + j) * 256];
            }
            uint4 ah, al, bh, bl;
            unsigned* ahp = (unsigned*)&ah; unsigned* alp = (unsigned*)&al;
            unsigned* bhp = (unsigned*)&bh; unsigned* blp = (unsigned*)&bl;
            #pragma unroll
            for (int j2 = 0; j2 < 4; ++j2) {
                _Float16 h0 = (_Float16)av[j2 * 2], h1 = (_Float16)av[j2 * 2 + 1];
                ahp[j2] = (unsigned)(unsigned short)__builtin_bit_cast(short, h0)
                        | ((unsigned)(unsigned short)__builtin_bit_cast(short, h1) << 16);
                alp[j2] = (unsigned)(unsigned short)f2h(av[j2 * 2] - (float)h0)
                        | ((unsigned)(unsigned short)f2h(av[j2 * 2 + 1] - (float)h1) << 16);
                _Float16 g0 = (_Float16)bv[j2 * 2], g1 = (_Float16)bv[j2 * 2 + 1];
                bhp[j2] = (unsigned)(unsigned short)__builtin_bit_cast(short, g0)
                        | ((unsigned)(unsigned short)__builtin_bit_cast(short, g1) << 16);
                blp[j2] = (unsigned)(unsigned short)f2h(bv[j2 * 2] - (float)g0)
                        | ((unsigned)(unsigned short)f2h(bv[j2 * 2 + 1] - (float)g1) << 16);
            }
            int gi = (it * 256 + mm * 4 + wq) * 8;
            *(uint4*)(Abh + gi) = ah;
            *(uint4*)(Abl + gi) = al;
            *(uint4*)(Bbh + gi) = bh;
            *(uint4*)(Bbl + gi) = bl;
        }
        __syncthreads();

        #pragma unroll
        for (int kc = 0; kc < 2; ++kc) {
            int ga = (kc * 256 + (w * 16 + l15) * 4 + quad) * 8;
            f16x8 ah = *(const f16x8*)(Abh + ga);
            f16x8 al = *(const f16x8*)(Abl + ga);
            #pragma unroll
            for (int nt = 0; nt < 4; ++nt) {
                int gb = (kc * 256 + (nt * 16 + l15) * 4 + quad) * 8;
                f16x8 bh = *(const f16x8*)(Bbh + gb);
                f16x8 bl = *(const f16x8*)(Bbl + gb);
                acc[nt] = __builtin_amdgcn_mfma_f32_16x16x32_f16(ah, bh, acc[nt], 0, 0, 0);
                acc[nt] = __builtin_amdgcn_mfma_f32_16x16x32_f16(ah, bl, acc[nt], 0, 0, 0);
                acc[nt] = __builtin_amdgcn_mfma_f32_16x16x32_f16(al, bh, acc[nt], 0, 0, 0);
            }
        }
        __syncthreads();
    }

    #pragma unroll
    for (int nt = 0; nt < 4; ++nt) {
        int n = n0 + nt * 16 + l15;
        float bs = bias[n];
        #pragma unroll
        for (int r = 0; r < 4; ++r) {
            int row = m0 + w * 16 + quad * 4 + r;
            if (row < M)
                Y[(size_t)row * 256 + n] = acc[nt][r] + bs;
        }
    }
}

// ---------------------------------------------------------------------------
// RPE via fp16-split MFMA. W2 hi/lo split (x LOG2E) done in-block.
// ---------------------------------------------------------------------------
__global__ __launch_bounds__(256) void rpe2_kernel(
    const float* __restrict__ ref2d,
    const float* __restrict__ W1x, const float* __restrict__ b1x,
    const float* __restrict__ W1y, const float* __restrict__ b1y,
    const float* __restrict__ W2x, const float* __restrict__ W2y,
    float* __restrict__ rpe_x, float* __restrict__ rpe_y)
{
    __shared__ short sw2h[8192], sw2l[8192];
    __shared__ float4 sW1i[512];
    __shared__ float2 sB1i[512];
    __shared__ short hxh[64 * 40], hxl[64 * 40], hyh[64 * 40], hyl[64 * 40];

    const int tid = threadIdx.x;
    const int bq = blockIdx.x;
    for (int i = tid; i < 512; i += 256) {
        sW1i[i] = make_float4(W1x[i], W1x[512 + i], W1y[i], W1y[512 + i]);
        sB1i[i] = make_float2(b1x[i], b1y[i]);
    }
    for (int i = tid; i < 8192; i += 256) {
        int g = i >> 3, j = i & 7;
        int kcg = g >> 6, rr = g & 63, n = rr >> 2, q4 = rr & 3;
        int k = kcg * 32 + q4 * 8 + j;
        float val = ((n < 8) ? W2x[k * 8 + n] : W2y[k * 8 + (n - 8)]) * LOG2E;
        _Float16 hi = (_Float16)val;
        sw2h[i] = __builtin_bit_cast(short, hi);
        sw2l[i] = f2h(val - (float)hi);
    }
    const float4 box = *(const float4*)(ref2d + (size_t)bq * 4);

    const int w = tid >> 6, l = tid & 63, quad = l >> 4, l15 = l & 15;
    const int r = l;
    const float pc = (r + 0.5f) * 16.0f;
    const float dx0 = (box.x - box.z * 0.5f) - pc;
    const float dx1 = (box.x + box.z * 0.5f) - pc;
    const float dy0 = (box.y - box.w * 0.5f) - pc;
    const float dy1 = (box.y + box.w * 0.5f) - pc;

    f32x4 accx = {0.f, 0.f, 0.f, 0.f}, accy = {0.f, 0.f, 0.f, 0.f};
    __syncthreads();

    for (int kc = 0; kc < 16; ++kc) {
        unsigned short vxh[8], vxl[8], vyh[8], vyl[8];
        #pragma unroll
        for (int i = 0; i < 8; ++i) {
            int j = kc * 32 + w * 8 + i;
            float4 w1 = sW1i[j];
            float2 bb = sB1i[j];
            float hx = fmaxf(fmaf(dx0, w1.x, fmaf(dx1, w1.y, bb.x)), 0.f);
            float hy = fmaxf(fmaf(dy0, w1.z, fmaf(dy1, w1.w, bb.y)), 0.f);
            _Float16 xh = (_Float16)hx;
            _Float16 yh = (_Float16)hy;
            vxh[i] = (unsigned short)__builtin_bit_cast(short, xh);
            vyh[i] = (unsigned short)__builtin_bit_cast(short, yh);
            vxl[i] = (unsigned short)f2h(hx - (float)xh);
            vyl[i] = (unsigned short)f2h(hy - (float)yh);
        }
        __syncthreads();
        uint4 p;
        p.x = vxh[0] | ((unsigned)vxh[1] << 16); p.y = vxh[2] | ((unsigned)vxh[3] << 16);
        p.z = vxh[4] | ((unsigned)vxh[5] << 16); p.w = vxh[6] | ((unsigned)vxh[7] << 16);
        *(uint4*)(hxh + r * 40 + w * 8) = p;
        p.x = vxl[0] | ((unsigned)vxl[1] << 16); p.y = vxl[2] | ((unsigned)vxl[3] << 16);
        p.z = vxl[4] | ((unsigned)vxl[5] << 16); p.w = vxl[6] | ((unsigned)vxl[7] << 16);
        *(uint4*)(hxl + r * 40 + w * 8) = p;
        p.x = vyh[0] | ((unsigned)vyh[1] << 16); p.y = vyh[2] | ((unsigned)vyh[3] << 16);
        p.z = vyh[4] | ((unsigned)vyh[5] << 16); p.w = vyh[6] | ((unsigned)vyh[7] << 16);
        *(uint4*)(hyh + r * 40 + w * 8) = p;
        p.x = vyl[0] | ((unsigned)vyl[1] << 16); p.y = vyl[2] | ((unsigned)vyl[3] << 16);
        p.z = vyl[4] | ((unsigned)vyl[5] << 16); p.w = vyl[6] | ((unsigned)vyl[7] << 16);
        *(uint4*)(hyl + r * 40 + w * 8) = p;
        __syncthreads();

        f16x8 axh = *(const f16x8*)(hxh + (w * 16 + l15) * 40 + quad * 8);
        f16x8 axl = *(const f16x8*)(hxl + (w * 16 + l15) * 40 + quad * 8);
        f16x8 ayh = *(const f16x8*)(hyh + (w * 16 + l15) * 40 + quad * 8);
        f16x8 ayl = *(const f16x8*)(hyl + (w * 16 + l15) * 40 + quad * 8);
        f16x8 bh = *(const f16x8*)(sw2h + (kc * 64 + l15 * 4 + quad) * 8);
        f16x8 bl = *(const f16x8*)(sw2l + (kc * 64 + l15 * 4 + quad) * 8);
        accx = __builtin_amdgcn_mfma_f32_16x16x32_f16(axh, bh, accx, 0, 0, 0);
        accx = __builtin_amdgcn_mfma_f32_16x16x32_f16(axh, bl, accx, 0, 0, 0);
        accx = __builtin_amdgcn_mfma_f32_16x16x32_f16(axl, bh, accx, 0, 0, 0);
        accy = __builtin_amdgcn_mfma_f32_16x16x32_f16(ayh, bh, accy, 0, 0, 0);
        accy = __builtin_amdgcn_mfma_f32_16x16x32_f16(ayh, bl, accy, 0, 0, 0);
        accy = __builtin_amdgcn_mfma_f32_16x16x32_f16(ayl, bh, accy, 0, 0, 0);
    }

    #pragma unroll
    for (int rr = 0; rr < 4; ++rr) {
        int row = w * 16 + quad * 4 + rr;
        size_t base = ((size_t)bq * 64 + row) * 8;
        if (l15 < 8) rpe_x[base + l15] = accx[rr];
        else         rpe_y[base + (l15 - 8)] = accy[rr];
    }
}

// ---------------------------------------------------------------------------
// MFMA flash attention. Round-8 structure (LDS diet: no rx tile, ballot
// bitmask mask, obuf in skf) but launch_bounds (512,4): round 8's (512,6)
// forced VGPR 40 -> scratch spills (WRITE_SIZE 49 MB, FETCH 205 MB, 2x dur).
// 2 blocks/CU spill-free beats 3 blocks/CU spilled.
// ---------------------------------------------------------------------------
__global__ __launch_bounds__(512, 4) void attn_mfma_kernel(
    const unsigned short* __restrict__ qb16, const unsigned short* __restrict__ kb16,
    const unsigned short* __restrict__ vb16,
    const float* __restrict__ rpe_x, const float* __restrict__ rpe_y,
    const unsigned char* __restrict__ mask, float* __restrict__ xout)
{
    __shared__ short skf[4 * 2048];      // 16 KB K frags; reused as obuf
    __shared__ short svt[4 * 2048];      // 16 KB V^T (XOR-swizzled granules)
    __shared__ short spb[8 * 544];       // 8.7 KB P buf per wave
    __shared__ float ry[32 * 65];        // 8.3 KB
    __shared__ unsigned long long smaskb[64];
    __shared__ float sm[8][16], sl[8][16], sLf[32];

    const int tid = threadIdx.x;
    const int qb = blockIdx.x, h = blockIdx.y, b = blockIdx.z;
    const int q0 = qb * 32;
    const int w = tid >> 6, l = tid & 63;
    const int qsub = w >> 2, g = w & 3;
    const int quad = l >> 4, l15 = l & 15;

    const unsigned short* qg = qb16 + (size_t)(b * 8 + h) * 960 * 32;
    const unsigned short* kg = kb16 + (size_t)(b * 8 + h) * 4096 * 32;
    const unsigned short* vg = vb16 + (size_t)(b * 8 + h) * 4096 * 32;

    for (int i = tid; i < 2048; i += 512) {
        int qq = q0 + (i >> 6), pos = i & 63;
        float vy = 0.f;
        if (qq < NQ_)
            vy = rpe_y[((size_t)(b * NQ_ + qq) * 64 + pos) * 8 + h];
        ry[(i >> 6) * 65 + pos] = vy;
    }
    #pragma unroll
    for (int j = 0; j < 8; ++j) {
        int c = w * 8 + j;
        unsigned long long bits = __ballot(mask[(size_t)b * N_ + c * 64 + l] != 0);
        if (l == 0) smaskb[c] = bits;
    }

    s16x8 qa = *(const s16x8*)(qg + (size_t)(q0 + qsub * 16 + l15) * 32 + quad * 8);

    // rpe_x fragment straight from global (L2-resident), as MFMA C-operand
    f32x4 rx4[4];
    #pragma unroll
    for (int t = 0; t < 4; ++t)
        #pragma unroll
        for (int r = 0; r < 4; ++r) {
            int qq = q0 + qsub * 16 + quad * 4 + r;
            rx4[t][r] = (qq < NQ_)
                ? rpe_x[((size_t)(b * NQ_ + qq) * 64 + t * 16 + l15) * 8 + h] : 0.f;
        }

    const int sg = tid >> 7, role = (tid >> 6) & 1, stl = tid & 63;
    int eoff[4];
    if (role == 0) {
        #pragma unroll
        for (int t = 0; t < 4; ++t)
            eoff[t] = (t * 16 + (stl & 15)) * 32 + (stl >> 4) * 8;
    } else {
        #pragma unroll
        for (int t = 0; t < 4; ++t)
            eoff[t] = stl * 32 + t * 8;
    }
    const unsigned short* src = role ? vg : kg;

    uint4 pf[4];
    {
        size_t cb = (size_t)(sg * 16) * 2048;
        #pragma unroll
        for (int t = 0; t < 4; ++t) pf[t] = *(const uint4*)(src + cb + eoff[t]);
    }

    float mrow[4] = {-INFINITY, -INFINITY, -INFINITY, -INFINITY};
    float lrow[4] = {0.f, 0.f, 0.f, 0.f};
    f32x4 acc0 = {0.f, 0.f, 0.f, 0.f}, acc1 = {0.f, 0.f, 0.f, 0.f};
    short* pw = spb + w * 544;

    for (int i = 0; i < 16; ++i) {
        __syncthreads();
        if (role == 0) {
            #pragma unroll
            for (int t = 0; t < 4; ++t)
                *(uint4*)(skf + sg * 2048 + (t * 64 + stl) * 8) = pf[t];
        } else {
            short* vtw = svt + sg * 2048;
            #pragma unroll
            for (int t = 0; t < 4; ++t) {
                const unsigned short* pv = (const unsigned short*)&pf[t];
                #pragma unroll
                for (int j = 0; j < 8; ++j) {
                    int d = t * 8 + j;
                    vtw[d * 64 + (((stl >> 3) ^ (d & 7)) << 3) + (stl & 7)] = (short)pv[j];
                }
            }
        }
        __syncthreads();

        {
            int inext = (i + 1 < 16) ? i + 1 : 15;
            size_t cb = (size_t)(sg * 16 + inext) * 2048;
            #pragma unroll
            for (int t = 0; t < 4; ++t) pf[t] = *(const uint4*)(src + cb + eoff[t]);
        }

        const int cgc = g * 16 + i;
        const short* kf = skf + g * 2048;

        f32x4 sc[4];
        #pragma unroll
        for (int t = 0; t < 4; ++t) {
            s16x8 kb = *(const s16x8*)(kf + (t * 64 + l) * 8);
            sc[t] = __builtin_amdgcn_mfma_f32_16x16x32_bf16(qa, kb, rx4[t], 0, 0, 0);
        }
        float ryv[4];
        #pragma unroll
        for (int r = 0; r < 4; ++r)
            ryv[r] = ry[(qsub * 16 + quad * 4 + r) * 65 + cgc];
        unsigned long long mb = smaskb[cgc];
        if (mb) {
            #pragma unroll
            for (int t = 0; t < 4; ++t) {
                float mk = ((mb >> (t * 16 + l15)) & 1ULL) ? -144.2695f : 0.f;
                #pragma unroll
                for (int r = 0; r < 4; ++r) sc[t][r] += mk;
            }
        }
        #pragma unroll
        for (int t = 0; t < 4; ++t)
            #pragma unroll
            for (int r = 0; r < 4; ++r)
                sc[t][r] += ryv[r];

        float cm[4];
        #pragma unroll
        for (int r = 0; r < 4; ++r) {
            cm[r] = fmaxf(fmaxf(sc[0][r], sc[1][r]), fmaxf(sc[2][r], sc[3][r]));
            cm[r] = rowmax16(cm[r]);
        }
        float al[4];
        #pragma unroll
        for (int r = 0; r < 4; ++r) {
            float mnew = fmaxf(mrow[r], cm[r]);
            al[r] = exp2f(mrow[r] - mnew);
            mrow[r] = mnew;
            lrow[r] *= al[r];
            acc0[r] *= al[r];
            acc1[r] *= al[r];
        }
        #pragma unroll
        for (int t = 0; t < 4; ++t)
            #pragma unroll
            for (int r = 0; r < 4; ++r)
                sc[t][r] = exp2f(sc[t][r] - mrow[r]);
        #pragma unroll
        for (int r = 0; r < 4; ++r) {
            float rs = (sc[0][r] + sc[1][r]) + (sc[2][r] + sc[3][r]);
            lrow[r] += rowsum16(rs);
        }

        const short* vt = svt + g * 2048;
        #pragma unroll
        for (int hh = 0; hh < 2; ++hh) {
            #pragma unroll
            for (int tt = 0; tt < 2; ++tt) {
                int t = hh * 2 + tt;
                int gphys = (tt * 2 + (l15 >> 3)) ^ quad;
                #pragma unroll
                for (int r = 0; r < 4; ++r)
                    pw[(gphys * 17 + quad * 4 + r) * 8 + (l15 & 7)] = f2bf(sc[t][r]);
            }
            int gph_r = quad ^ (l15 >> 2);
            s16x8 pa  = *(const s16x8*)(pw + (gph_r * 17 + l15) * 8);
            int ksw = ((hh * 4 + quad) ^ (l15 & 7)) * 8;
            s16x8 vb0 = *(const s16x8*)(vt + l15 * 64 + ksw);
            s16x8 vb1 = *(const s16x8*)(vt + (16 + l15) * 64 + ksw);
            acc0 = __builtin_amdgcn_mfma_f32_16x16x32_bf16(pa, vb0, acc0, 0, 0, 0);
            acc1 = __builtin_amdgcn_mfma_f32_16x16x32_bf16(pa, vb1, acc1, 0, 0, 0);
        }
    }

    __syncthreads();
    if (l15 == 0) {
        #pragma unroll
        for (int r = 0; r < 4; ++r) {
            sm[w][quad * 4 + r] = mrow[r];
            sl[w][quad * 4 + r] = lrow[r];
        }
    }
    __syncthreads();
    float wgt[4], L4[4];
    #pragma unroll
    for (int r = 0; r < 4; ++r) {
        int qrow = quad * 4 + r;
        float mm = -INFINITY;
        #pragma unroll
        for (int gg = 0; gg < 4; ++gg) mm = fmaxf(mm, sm[qsub * 4 + gg][qrow]);
        float LL = 0.f;
        #pragma unroll
        for (int gg = 0; gg < 4; ++gg)
            LL += exp2f(sm[qsub * 4 + gg][qrow] - mm) * sl[qsub * 4 + gg][qrow];
        wgt[r] = exp2f(mrow[r] - mm);
        L4[r] = LL;
    }
    if (g == 0 && l15 == 0) {
        #pragma unroll
        for (int r = 0; r < 4; ++r) sLf[qsub * 16 + quad * 4 + r] = L4[r];
    }

    float* obuf = (float*)skf;
    for (int gg = 0; gg < 4; ++gg) {
        if (g == gg) {
            #pragma unroll
            for (int r = 0; r < 4; ++r) {
                int idx = (qsub * 16 + quad * 4 + r) * 33 + l15;
                float v0 = wgt[r] * acc0[r];
                float v1 = wgt[r] * acc1[r];
                if (gg == 0) { obuf[idx] = v0; obuf[idx + 16] = v1; }
                else         { obuf[idx] += v0; obuf[idx + 16] += v1; }
            }
        }
        __syncthreads();
    }

    for (int i = tid; i < 1024; i += 512) {
        int ql = i >> 5, d = i & 31;
        int qq = q0 + ql;
        if (qq < NQ_)
            xout[(size_t)(b * NQ_ + qq) * 256 + h * 32 + d] = obuf[ql * 33 + d] / sLf[ql];
    }
}

// ---------------------------------------------------------------------------
extern "C" void kernel_launch(void* const* d_in, const int* in_sizes, int n_in,
                              void* d_out, int out_size, void* d_ws, size_t ws_size,
                              hipStream_t stream)
{
    const float* query = (const float*)d_in[1];
    const float* ref2d = (const float*)d_in[2];
    const float* kin   = (const float*)d_in[3];
    const float* vin   = (const float*)d_in[4];
    const unsigned char* mask = (const unsigned char*)d_in[6];
    const float* W1x = (const float*)d_in[7];
    const float* b1x = (const float*)d_in[8];
    const float* W2x = (const float*)d_in[9];
    const float* W1y = (const float*)d_in[10];
    const float* b1y = (const float*)d_in[11];
    const float* W2y = (const float*)d_in[12];
    const float* Wq  = (const float*)d_in[13];
    const float* bq  = (const float*)d_in[14];
    const float* Wk  = (const float*)d_in[15];
    const float* bk  = (const float*)d_in[16];
    const float* Wv  = (const float*)d_in[17];
    const float* bv  = (const float*)d_in[18];
    const float* Wp  = (const float*)d_in[19];
    const float* bp  = (const float*)d_in[20];

    // Workspace ~18.6 MB (proven-safe footprint 27.8 MB)
    char* wsb = (char*)d_ws;
    unsigned short* qbf = (unsigned short*)(wsb);               //   983040 B
    unsigned short* kbf = (unsigned short*)(wsb +   983040);    //  4194304 B
    unsigned short* vbf = (unsigned short*)(wsb +  5177344);    //  4194304 B
    float* rxws = (float*)(wsb +  9371648);                     //  3686400 B
    float* ryws = (float*)(wsb + 13058048);                     //  3686400 B
    float* xws  = (float*)(wsb + 16744448);                     //  1843200 B
    float* out  = (float*)d_out;

    const float qscale = LOG2E / sqrtf(32.0f);   // exp2-domain softmax

    proj_kernel<<<dim3(128, 1, 3), 256, 0, stream>>>(
        query, kin, vin, Wq, Wk, Wv, bq, bk, bv, qbf, kbf, vbf, qscale);
    rpe2_kernel<<<1800, 256, 0, stream>>>(
        ref2d, W1x, b1x, W1y, b1y, W2x, W2y, rxws, ryws);
    attn_mfma_kernel<<<dim3(29, 8, B_), 512, 0, stream>>>(
        qbf, kbf, vbf, rxws, ryws, mask, xws);
    outproj_kernel<<<dim3(29, 4), 256, 0, stream>>>(xws, Wp, bp, out, 1800);
}

// Round 10
// 245.713 us; speedup vs baseline: 1.3777x; 1.1254x over previous
//
#include <hip/hip_runtime.h>
#include <hip/hip_bf16.h>
#include <cmath>

// Problem constants
#define B_ 2
#define NQ_ 900
#define N_ 4096
#define LOG2E 1.4426950408889634f

typedef __attribute__((ext_vector_type(4))) float f32x4;
typedef __attribute__((ext_vector_type(8))) short s16x8;
typedef __attribute__((ext_vector_type(8))) _Float16 f16x8;

__device__ inline short f2bf(float x) {
    union { __hip_bfloat16 b; short s; } u;
    u.b = __float2bfloat16(x);
    return u.s;
}
__device__ inline short f2h(float x) {
    _Float16 h = (_Float16)x;
    return __builtin_bit_cast(short, h);
}

// DPP rotate within 16-lane row (VALU pipe; replaces ds_bpermute shuffles)
template <int CTRL>
__device__ inline float dppf(float x) {
    int xi = __builtin_bit_cast(int, x);
    int r = __builtin_amdgcn_update_dpp(xi, xi, CTRL, 0xF, 0xF, true);
    return __builtin_bit_cast(float, r);
}
__device__ inline float rowmax16(float v) {
    v = fmaxf(v, dppf<0x121>(v));
    v = fmaxf(v, dppf<0x122>(v));
    v = fmaxf(v, dppf<0x124>(v));
    v = fmaxf(v, dppf<0x128>(v));
    return v;
}
__device__ inline float rowsum16(float v) {
    v += dppf<0x121>(v);
    v += dppf<0x122>(v);
    v += dppf<0x124>(v);
    v += dppf<0x128>(v);
    return v;
}

// ---------------------------------------------------------------------------
// Merged Q/K/V projection. MFMA bf16, 64-row tile, K=256 LDS-resident A
// staged once; four 64-col n-tiles looped in-block. (unchanged from round 9)
// ---------------------------------------------------------------------------
__global__ __launch_bounds__(256) void proj_kernel(
    const float* __restrict__ query, const float* __restrict__ kin,
    const float* __restrict__ vin,
    const float* __restrict__ Wq, const float* __restrict__ Wk,
    const float* __restrict__ Wv,
    const float* __restrict__ bqv, const float* __restrict__ bkv,
    const float* __restrict__ bvv,
    unsigned short* __restrict__ qbf, unsigned short* __restrict__ kbf,
    unsigned short* __restrict__ vbf, float qscale)
{
    const int mtx = blockIdx.z;
    const float* X = mtx == 0 ? query : mtx == 1 ? kin : vin;
    const float* W = mtx == 0 ? Wq : mtx == 1 ? Wk : Wv;
    const float* bias = mtx == 0 ? bqv : mtx == 1 ? bkv : bvv;
    unsigned short* Y = mtx == 0 ? qbf : mtx == 1 ? kbf : vbf;
    const int M = mtx == 0 ? 1800 : 8192;
    const int m0 = blockIdx.x * 64;
    if (m0 >= M) return;
    const float alpha = mtx == 0 ? qscale : 1.0f;
    const int rows_per_b = mtx == 0 ? 900 : 4096;
    const int ROWS = mtx == 0 ? 960 : 4096;

    __shared__ short Ab[16384];
    __shared__ short Bb[16384];
    const int tid = threadIdx.x;
    const int w = tid >> 6, l = tid & 63, quad = l >> 4, l15 = l & 15;
    const int wq = tid & 3, mm = tid >> 2;

    {
        const bool valid = (m0 + mm) < M;
        const float* xr = X + (size_t)(m0 + mm) * 256;
        #pragma unroll
        for (int it = 0; it < 8; ++it) {
            int g2 = it * 4 + wq;
            float4 a0 = make_float4(0.f, 0.f, 0.f, 0.f), a1 = a0;
            if (valid) {
                a0 = *(const float4*)(xr + g2 * 8);
                a1 = *(const float4*)(xr + g2 * 8 + 4);
            }
            uint4 pk;
            pk.x = (unsigned)(unsigned short)f2bf(a0.x) | ((unsigned)(unsigned short)f2bf(a0.y) << 16);
            pk.y = (unsigned)(unsigned short)f2bf(a0.z) | ((unsigned)(unsigned short)f2bf(a0.w) << 16);
            pk.z = (unsigned)(unsigned short)f2bf(a1.x) | ((unsigned)(unsigned short)f2bf(a1.y) << 16);
            pk.w = (unsigned)(unsigned short)f2bf(a1.z) | ((unsigned)(unsigned short)f2bf(a1.w) << 16);
            *(uint4*)(Ab + (it * 256 + mm * 4 + wq) * 8) = pk;
        }
    }

    for (int nt0 = 0; nt0 < 4; ++nt0) {
        const int n0 = nt0 * 64;
        {
            const float* wcol = W + n0 + mm;
            #pragma unroll
            for (int it = 0; it < 8; ++it) {
                int g2 = it * 4 + wq;
                uint4 wk4;
                wk4.x = (unsigned)(unsigned short)f2bf(wcol[(g2 * 8 + 0) * 256])
                      | ((unsigned)(unsigned short)f2bf(wcol[(g2 * 8 + 1) * 256]) << 16);
                wk4.y = (unsigned)(unsigned short)f2bf(wcol[(g2 * 8 + 2) * 256])
                      | ((unsigned)(unsigned short)f2bf(wcol[(g2 * 8 + 3) * 256]) << 16);
                wk4.z = (unsigned)(unsigned short)f2bf(wcol[(g2 * 8 + 4) * 256])
                      | ((unsigned)(unsigned short)f2bf(wcol[(g2 * 8 + 5) * 256]) << 16);
                wk4.w = (unsigned)(unsigned short)f2bf(wcol[(g2 * 8 + 6) * 256])
                      | ((unsigned)(unsigned short)f2bf(wcol[(g2 * 8 + 7) * 256]) << 16);
                *(uint4*)(Bb + (it * 256 + mm * 4 + wq) * 8) = wk4;
            }
        }
        __syncthreads();

        f32x4 acc[4] = {{0.f,0.f,0.f,0.f},{0.f,0.f,0.f,0.f},{0.f,0.f,0.f,0.f},{0.f,0.f,0.f,0.f}};
        #pragma unroll
        for (int kc = 0; kc < 8; ++kc) {
            s16x8 a = *(const s16x8*)(Ab + (kc * 256 + (w * 16 + l15) * 4 + quad) * 8);
            #pragma unroll
            for (int nt = 0; nt < 4; ++nt) {
                s16x8 bf = *(const s16x8*)(Bb + (kc * 256 + (nt * 16 + l15) * 4 + quad) * 8);
                acc[nt] = __builtin_amdgcn_mfma_f32_16x16x32_bf16(a, bf, acc[nt], 0, 0, 0);
            }
        }
        __syncthreads();

        #pragma unroll
        for (int nt = 0; nt < 4; ++nt) {
            int n = n0 + nt * 16 + l15;
            float bs = bias[n];
            int h = n >> 5, d = n & 31;
            #pragma unroll
            for (int r = 0; r < 4; ++r) {
                int row = m0 + w * 16 + quad * 4 + r;
                if (row < M) {
                    int b = row / rows_per_b;
                    int pos = row - b * rows_per_b;
                    Y[((size_t)(b * 8 + h) * ROWS + pos) * 32 + d] =
                        (unsigned short)f2bf((acc[nt][r] + bs) * alpha);
                }
            }
        }
    }
}

// ---------------------------------------------------------------------------
// Output projection via fp16 hi/lo split MFMA (unchanged from round 9).
// ---------------------------------------------------------------------------
__global__ __launch_bounds__(256) void outproj_kernel(
    const float* __restrict__ X, const float* __restrict__ W,
    const float* __restrict__ bias, float* __restrict__ Y, int M)
{
    __shared__ short Abh[4096], Abl[4096], Bbh[4096], Bbl[4096];
    const int tid = threadIdx.x;
    const int m0 = blockIdx.x * 64, n0 = blockIdx.y * 64;
    const int w = tid >> 6, l = tid & 63, quad = l >> 4, l15 = l & 15;
    const int wq = tid & 3, mm = tid >> 2;
    const bool valid = (m0 + mm) < M;
    const float* xr = X + (size_t)(m0 + mm) * 256;
    const float* wcol = W + n0 + mm;

    f32x4 acc[4] = {{0.f,0.f,0.f,0.f},{0.f,0.f,0.f,0.f},{0.f,0.f,0.f,0.f},{0.f,0.f,0.f,0.f}};

    for (int kq = 0; kq < 4; ++kq) {
        #pragma unroll
        for (int it = 0; it < 2; ++it) {
            int g2 = it * 4 + wq;
            int kbase = kq * 64 + g2 * 8;
            float av[8], bv[8];
            #pragma unroll
            for (int j = 0; j < 8; ++j) {
                av[j] = valid ? xr[kbase + j] : 0.f;
                bv[j] = wcol[(kbase + j) * 256];
            }
            uint4 ah, al, bh, bl;
            unsigned* ahp = (unsigned*)&ah; unsigned* alp = (unsigned*)&al;
            unsigned* bhp = (unsigned*)&bh; unsigned* blp = (unsigned*)&bl;
            #pragma unroll
            for (int j2 = 0; j2 < 4; ++j2) {
                _Float16 h0 = (_Float16)av[j2 * 2], h1 = (_Float16)av[j2 * 2 + 1];
                ahp[j2] = (unsigned)(unsigned short)__builtin_bit_cast(short, h0)
                        | ((unsigned)(unsigned short)__builtin_bit_cast(short, h1) << 16);
                alp[j2] = (unsigned)(unsigned short)f2h(av[j2 * 2] - (float)h0)
                        | ((unsigned)(unsigned short)f2h(av[j2 * 2 + 1] - (float)h1) << 16);
                _Float16 g0 = (_Float16)bv[j2 * 2], g1 = (_Float16)bv[j2 * 2 + 1];
                bhp[j2] = (unsigned)(unsigned short)__builtin_bit_cast(short, g0)
                        | ((unsigned)(unsigned short)__builtin_bit_cast(short, g1) << 16);
                blp[j2] = (unsigned)(unsigned short)f2h(bv[j2 * 2] - (float)g0)
                        | ((unsigned)(unsigned short)f2h(bv[j2 * 2 + 1] - (float)g1) << 16);
            }
            int gi = (it * 256 + mm * 4 + wq) * 8;
            *(uint4*)(Abh + gi) = ah;
            *(uint4*)(Abl + gi) = al;
            *(uint4*)(Bbh + gi) = bh;
            *(uint4*)(Bbl + gi) = bl;
        }
        __syncthreads();

        #pragma unroll
        for (int kc = 0; kc < 2; ++kc) {
            int ga = (kc * 256 + (w * 16 + l15) * 4 + quad) * 8;
            f16x8 ah = *(const f16x8*)(Abh + ga);
            f16x8 al = *(const f16x8*)(Abl + ga);
            #pragma unroll
            for (int nt = 0; nt < 4; ++nt) {
                int gb = (kc * 256 + (nt * 16 + l15) * 4 + quad) * 8;
                f16x8 bh = *(const f16x8*)(Bbh + gb);
                f16x8 bl = *(const f16x8*)(Bbl + gb);
                acc[nt] = __builtin_amdgcn_mfma_f32_16x16x32_f16(ah, bh, acc[nt], 0, 0, 0);
                acc[nt] = __builtin_amdgcn_mfma_f32_16x16x32_f16(ah, bl, acc[nt], 0, 0, 0);
                acc[nt] = __builtin_amdgcn_mfma_f32_16x16x32_f16(al, bh, acc[nt], 0, 0, 0);
            }
        }
        __syncthreads();
    }

    #pragma unroll
    for (int nt = 0; nt < 4; ++nt) {
        int n = n0 + nt * 16 + l15;
        float bs = bias[n];
        #pragma unroll
        for (int r = 0; r < 4; ++r) {
            int row = m0 + w * 16 + quad * 4 + r;
            if (row < M)
                Y[(size_t)row * 256 + n] = acc[nt][r] + bs;
        }
    }
}

// ---------------------------------------------------------------------------
// RPE v3: per-lane direct layer-1 into MFMA A-fragments (no hidden LDS
// round-trip — round 9's stride-40 hxh/hxl tiles caused 2.76M bank-conflict
// cycles + 32 barriers/block). Lane (quad,l15) of wave w computes hidden
// h[row=(w&3)*16+l15][k=quad*8+i] directly (layer-1 is elementwise in row,k).
// 512 threads = 2 queries/block; W1 padded to 9-float4 granules so the 4
// quad broadcast addresses hit disjoint bank groups. One barrier total.
// ---------------------------------------------------------------------------
__global__ __launch_bounds__(512) void rpe3_kernel(
    const float* __restrict__ ref2d,
    const float* __restrict__ W1x, const float* __restrict__ b1x,
    const float* __restrict__ W1y, const float* __restrict__ b1y,
    const float* __restrict__ W2x, const float* __restrict__ W2y,
    float* __restrict__ rpe_x, float* __restrict__ rpe_y)
{
    __shared__ short sw2h[8192], sw2l[8192];   // 16+16 KB, B-frag granule order
    __shared__ float4 sW1p[576];               // (g*9+i) padded, 9.2 KB
    __shared__ float2 sB1p[576];               // 4.6 KB

    const int tid = threadIdx.x;
    for (int i = tid; i < 8192; i += 512) {
        int g = i >> 3, j = i & 7;
        int kcg = g >> 6, rr = g & 63, n = rr >> 2, q4 = rr & 3;
        int k = kcg * 32 + q4 * 8 + j;
        float val = ((n < 8) ? W2x[k * 8 + n] : W2y[k * 8 + (n - 8)]) * LOG2E;
        _Float16 hi = (_Float16)val;
        sw2h[i] = __builtin_bit_cast(short, hi);
        sw2l[i] = f2h(val - (float)hi);
    }
    if (tid < 512) {
        int i = tid;
        sW1p[(i >> 3) * 9 + (i & 7)] = make_float4(W1x[i], W1x[512 + i], W1y[i], W1y[512 + i]);
        sB1p[(i >> 3) * 9 + (i & 7)] = make_float2(b1x[i], b1y[i]);
    }

    const int w = tid >> 6, l = tid & 63, quad = l >> 4, l15 = l & 15;
    const int qi = w >> 2, wrow = w & 3;
    const int bq = blockIdx.x * 2 + qi;
    const float4 box = *(const float4*)(ref2d + (size_t)bq * 4);
    const int row = wrow * 16 + l15;           // hidden row this lane computes
    const float pc = (row + 0.5f) * 16.0f;
    const float dx0 = (box.x - box.z * 0.5f) - pc;
    const float dx1 = (box.x + box.z * 0.5f) - pc;
    const float dy0 = (box.y - box.w * 0.5f) - pc;
    const float dy1 = (box.y + box.w * 0.5f) - pc;

    __syncthreads();

    f32x4 accx = {0.f, 0.f, 0.f, 0.f}, accy = {0.f, 0.f, 0.f, 0.f};
    for (int kc = 0; kc < 16; ++kc) {
        f16x8 axh, axl, ayh, ayl;
        #pragma unroll
        for (int i = 0; i < 8; ++i) {
            int gi = (kc * 4 + quad) * 9 + i;  // j = kc*32 + quad*8 + i
            float4 w1 = sW1p[gi];
            float2 bb = sB1p[gi];
            float hx = fmaxf(fmaf(dx0, w1.x, fmaf(dx1, w1.y, bb.x)), 0.f);
            float hy = fmaxf(fmaf(dy0, w1.z, fmaf(dy1, w1.w, bb.y)), 0.f);
            _Float16 xh = (_Float16)hx;
            _Float16 yh = (_Float16)hy;
            axh[i] = xh;
            axl[i] = (_Float16)(hx - (float)xh);
            ayh[i] = yh;
            ayl[i] = (_Float16)(hy - (float)yh);
        }
        f16x8 bh = *(const f16x8*)(sw2h + (kc * 64 + l15 * 4 + quad) * 8);
        f16x8 bl = *(const f16x8*)(sw2l + (kc * 64 + l15 * 4 + quad) * 8);
        accx = __builtin_amdgcn_mfma_f32_16x16x32_f16(axh, bh, accx, 0, 0, 0);
        accx = __builtin_amdgcn_mfma_f32_16x16x32_f16(axh, bl, accx, 0, 0, 0);
        accx = __builtin_amdgcn_mfma_f32_16x16x32_f16(axl, bh, accx, 0, 0, 0);
        accy = __builtin_amdgcn_mfma_f32_16x16x32_f16(ayh, bh, accy, 0, 0, 0);
        accy = __builtin_amdgcn_mfma_f32_16x16x32_f16(ayh, bl, accy, 0, 0, 0);
        accy = __builtin_amdgcn_mfma_f32_16x16x32_f16(ayl, bh, accy, 0, 0, 0);
    }

    #pragma unroll
    for (int rr = 0; rr < 4; ++rr) {
        int row_out = wrow * 16 + quad * 4 + rr;   // C layout: row = quad*4+reg
        size_t base = ((size_t)bq * 64 + row_out) * 8;
        if (l15 < 8) rpe_x[base + l15] = accx[rr];
        else         rpe_y[base + (l15 - 8)] = accy[rr];
    }
}

// ---------------------------------------------------------------------------
// MFMA flash attention (unchanged from round 9: (512,4) bounds, LDS diet,
// ballot bitmask, DPP softmax, exp2 domain).
// ---------------------------------------------------------------------------
__global__ __launch_bounds__(512, 4) void attn_mfma_kernel(
    const unsigned short* __restrict__ qb16, const unsigned short* __restrict__ kb16,
    const unsigned short* __restrict__ vb16,
    const float* __restrict__ rpe_x, const float* __restrict__ rpe_y,
    const unsigned char* __restrict__ mask, float* __restrict__ xout)
{
    __shared__ short skf[4 * 2048];
    __shared__ short svt[4 * 2048];
    __shared__ short spb[8 * 544];
    __shared__ float ry[32 * 65];
    __shared__ unsigned long long smaskb[64];
    __shared__ float sm[8][16], sl[8][16], sLf[32];

    const int tid = threadIdx.x;
    const int qb = blockIdx.x, h = blockIdx.y, b = blockIdx.z;
    const int q0 = qb * 32;
    const int w = tid >> 6, l = tid & 63;
    const int qsub = w >> 2, g = w & 3;
    const int quad = l >> 4, l15 = l & 15;

    const unsigned short* qg = qb16 + (size_t)(b * 8 + h) * 960 * 32;
    const unsigned short* kg = kb16 + (size_t)(b * 8 + h) * 4096 * 32;
    const unsigned short* vg = vb16 + (size_t)(b * 8 + h) * 4096 * 32;

    for (int i = tid; i < 2048; i += 512) {
        int qq = q0 + (i >> 6), pos = i & 63;
        float vy = 0.f;
        if (qq < NQ_)
            vy = rpe_y[((size_t)(b * NQ_ + qq) * 64 + pos) * 8 + h];
        ry[(i >> 6) * 65 + pos] = vy;
    }
    #pragma unroll
    for (int j = 0; j < 8; ++j) {
        int c = w * 8 + j;
        unsigned long long bits = __ballot(mask[(size_t)b * N_ + c * 64 + l] != 0);
        if (l == 0) smaskb[c] = bits;
    }

    s16x8 qa = *(const s16x8*)(qg + (size_t)(q0 + qsub * 16 + l15) * 32 + quad * 8);

    f32x4 rx4[4];
    #pragma unroll
    for (int t = 0; t < 4; ++t)
        #pragma unroll
        for (int r = 0; r < 4; ++r) {
            int qq = q0 + qsub * 16 + quad * 4 + r;
            rx4[t][r] = (qq < NQ_)
                ? rpe_x[((size_t)(b * NQ_ + qq) * 64 + t * 16 + l15) * 8 + h] : 0.f;
        }

    const int sg = tid >> 7, role = (tid >> 6) & 1, stl = tid & 63;
    int eoff[4];
    if (role == 0) {
        #pragma unroll
        for (int t = 0; t < 4; ++t)
            eoff[t] = (t * 16 + (stl & 15)) * 32 + (stl >> 4) * 8;
    } else {
        #pragma unroll
        for (int t = 0; t < 4; ++t)
            eoff[t] = stl * 32 + t * 8;
    }
    const unsigned short* src = role ? vg : kg;

    uint4 pf[4];
    {
        size_t cb = (size_t)(sg * 16) * 2048;
        #pragma unroll
        for (int t = 0; t < 4; ++t) pf[t] = *(const uint4*)(src + cb + eoff[t]);
    }

    float mrow[4] = {-INFINITY, -INFINITY, -INFINITY, -INFINITY};
    float lrow[4] = {0.f, 0.f, 0.f, 0.f};
    f32x4 acc0 = {0.f, 0.f, 0.f, 0.f}, acc1 = {0.f, 0.f, 0.f, 0.f};
    short* pw = spb + w * 544;

    for (int i = 0; i < 16; ++i) {
        __syncthreads();
        if (role == 0) {
            #pragma unroll
            for (int t = 0; t < 4; ++t)
                *(uint4*)(skf + sg * 2048 + (t * 64 + stl) * 8) = pf[t];
        } else {
            short* vtw = svt + sg * 2048;
            #pragma unroll
            for (int t = 0; t < 4; ++t) {
                const unsigned short* pv = (const unsigned short*)&pf[t];
                #pragma unroll
                for (int j = 0; j < 8; ++j) {
                    int d = t * 8 + j;
                    vtw[d * 64 + (((stl >> 3) ^ (d & 7)) << 3) + (stl & 7)] = (short)pv[j];
                }
            }
        }
        __syncthreads();

        {
            int inext = (i + 1 < 16) ? i + 1 : 15;
            size_t cb = (size_t)(sg * 16 + inext) * 2048;
            #pragma unroll
            for (int t = 0; t < 4; ++t) pf[t] = *(const uint4*)(src + cb + eoff[t]);
        }

        const int cgc = g * 16 + i;
        const short* kf = skf + g * 2048;

        f32x4 sc[4];
        #pragma unroll
        for (int t = 0; t < 4; ++t) {
            s16x8 kb = *(const s16x8*)(kf + (t * 64 + l) * 8);
            sc[t] = __builtin_amdgcn_mfma_f32_16x16x32_bf16(qa, kb, rx4[t], 0, 0, 0);
        }
        float ryv[4];
        #pragma unroll
        for (int r = 0; r < 4; ++r)
            ryv[r] = ry[(qsub * 16 + quad * 4 + r) * 65 + cgc];
        unsigned long long mb = smaskb[cgc];
        if (mb) {
            #pragma unroll
            for (int t = 0; t < 4; ++t) {
                float mk = ((mb >> (t * 16 + l15)) & 1ULL) ? -144.2695f : 0.f;
                #pragma unroll
                for (int r = 0; r < 4; ++r) sc[t][r] += mk;
            }
        }
        #pragma unroll
        for (int t = 0; t < 4; ++t)
            #pragma unroll
            for (int r = 0; r < 4; ++r)
                sc[t][r] += ryv[r];

        float cm[4];
        #pragma unroll
        for (int r = 0; r < 4; ++r) {
            cm[r] = fmaxf(fmaxf(sc[0][r], sc[1][r]), fmaxf(sc[2][r], sc[3][r]));
            cm[r] = rowmax16(cm[r]);
        }
        float al[4];
        #pragma unroll
        for (int r = 0; r < 4; ++r) {
            float mnew = fmaxf(mrow[r], cm[r]);
            al[r] = exp2f(mrow[r] - mnew);
            mrow[r] = mnew;
            lrow[r] *= al[r];
            acc0[r] *= al[r];
            acc1[r] *= al[r];
        }
        #pragma unroll
        for (int t = 0; t < 4; ++t)
            #pragma unroll
            for (int r = 0; r < 4; ++r)
                sc[t][r] = exp2f(sc[t][r] - mrow[r]);
        #pragma unroll
        for (int r = 0; r < 4; ++r) {
            float rs = (sc[0][r] + sc[1][r]) + (sc[2][r] + sc[3][r]);
            lrow[r] += rowsum16(rs);
        }

        const short* vt = svt + g * 2048;
        #pragma unroll
        for (int hh = 0; hh < 2; ++hh) {
            #pragma unroll
            for (int tt = 0; tt < 2; ++tt) {
                int t = hh * 2 + tt;
                int gphys = (tt * 2 + (l15 >> 3)) ^ quad;
                #pragma unroll
                for (int r = 0; r < 4; ++r)
                    pw[(gphys * 17 + quad * 4 + r) * 8 + (l15 & 7)] = f2bf(sc[t][r]);
            }
            int gph_r = quad ^ (l15 >> 2);
            s16x8 pa  = *(const s16x8*)(pw + (gph_r * 17 + l15) * 8);
            int ksw = ((hh * 4 + quad) ^ (l15 & 7)) * 8;
            s16x8 vb0 = *(const s16x8*)(vt + l15 * 64 + ksw);
            s16x8 vb1 = *(const s16x8*)(vt + (16 + l15) * 64 + ksw);
            acc0 = __builtin_amdgcn_mfma_f32_16x16x32_bf16(pa, vb0, acc0, 0, 0, 0);
            acc1 = __builtin_amdgcn_mfma_f32_16x16x32_bf16(pa, vb1, acc1, 0, 0, 0);
        }
    }

    __syncthreads();
    if (l15 == 0) {
        #pragma unroll
        for (int r = 0; r < 4; ++r) {
            sm[w][quad * 4 + r] = mrow[r];
            sl[w][quad * 4 + r] = lrow[r];
        }
    }
    __syncthreads();
    float wgt[4], L4[4];
    #pragma unroll
    for (int r = 0; r < 4; ++r) {
        int qrow = quad * 4 + r;
        float mm = -INFINITY;
        #pragma unroll
        for (int gg = 0; gg < 4; ++gg) mm = fmaxf(mm, sm[qsub * 4 + gg][qrow]);
        float LL = 0.f;
        #pragma unroll
        for (int gg = 0; gg < 4; ++gg)
            LL += exp2f(sm[qsub * 4 + gg][qrow] - mm) * sl[qsub * 4 + gg][qrow];
        wgt[r] = exp2f(mrow[r] - mm);
        L4[r] = LL;
    }
    if (g == 0 && l15 == 0) {
        #pragma unroll
        for (int r = 0; r < 4; ++r) sLf[qsub * 16 + quad * 4 + r] = L4[r];
    }

    float* obuf = (float*)skf;
    for (int gg = 0; gg < 4; ++gg) {
        if (g == gg) {
            #pragma unroll
            for (int r = 0; r < 4; ++r) {
                int idx = (qsub * 16 + quad * 4 + r) * 33 + l15;
                float v0 = wgt[r] * acc0[r];
                float v1 = wgt[r] * acc1[r];
                if (gg == 0) { obuf[idx] = v0; obuf[idx + 16] = v1; }
                else         { obuf[idx] += v0; obuf[idx + 16] += v1; }
            }
        }
        __syncthreads();
    }

    for (int i = tid; i < 1024; i += 512) {
        int ql = i >> 5, d = i & 31;
        int qq = q0 + ql;
        if (qq < NQ_)
            xout[(size_t)(b * NQ_ + qq) * 256 + h * 32 + d] = obuf[ql * 33 + d] / sLf[ql];
    }
}

// ---------------------------------------------------------------------------
extern "C" void kernel_launch(void* const* d_in, const int* in_sizes, int n_in,
                              void* d_out, int out_size, void* d_ws, size_t ws_size,
                              hipStream_t stream)
{
    const float* query = (const float*)d_in[1];
    const float* ref2d = (const float*)d_in[2];
    const float* kin   = (const float*)d_in[3];
    const float* vin   = (const float*)d_in[4];
    const unsigned char* mask = (const unsigned char*)d_in[6];
    const float* W1x = (const float*)d_in[7];
    const float* b1x = (const float*)d_in[8];
    const float* W2x = (const float*)d_in[9];
    const float* W1y = (const float*)d_in[10];
    const float* b1y = (const float*)d_in[11];
    const float* W2y = (const float*)d_in[12];
    const float* Wq  = (const float*)d_in[13];
    const float* bq  = (const float*)d_in[14];
    const float* Wk  = (const float*)d_in[15];
    const float* bk  = (const float*)d_in[16];
    const float* Wv  = (const float*)d_in[17];
    const float* bv  = (const float*)d_in[18];
    const float* Wp  = (const float*)d_in[19];
    const float* bp  = (const float*)d_in[20];

    // Workspace ~18.6 MB (proven-safe footprint 27.8 MB)
    char* wsb = (char*)d_ws;
    unsigned short* qbf = (unsigned short*)(wsb);               //   983040 B
    unsigned short* kbf = (unsigned short*)(wsb +   983040);    //  4194304 B
    unsigned short* vbf = (unsigned short*)(wsb +  5177344);    //  4194304 B
    float* rxws = (float*)(wsb +  9371648);                     //  3686400 B
    float* ryws = (float*)(wsb + 13058048);                     //  3686400 B
    float* xws  = (float*)(wsb + 16744448);                     //  1843200 B
    float* out  = (float*)d_out;

    const float qscale = LOG2E / sqrtf(32.0f);   // exp2-domain softmax

    proj_kernel<<<dim3(128, 1, 3), 256, 0, stream>>>(
        query, kin, vin, Wq, Wk, Wv, bq, bk, bv, qbf, kbf, vbf, qscale);
    rpe3_kernel<<<900, 512, 0, stream>>>(
        ref2d, W1x, b1x, W1y, b1y, W2x, W2y, rxws, ryws);
    attn_mfma_kernel<<<dim3(29, 8, B_), 512, 0, stream>>>(
        qbf, kbf, vbf, rxws, ryws, mask, xws);
    outproj_kernel<<<dim3(29, 4), 256, 0, stream>>>(xws, Wp, bp, out, 1800);
}